// Round 2
// baseline (516.417 us; speedup 1.0000x reference)
//
#include <hip/hip_runtime.h>
#include <stdint.h>

typedef __attribute__((ext_vector_type(8))) short short8;
typedef __attribute__((ext_vector_type(4))) float f32x4;

static __device__ __forceinline__ ushort f2bf(float f) {
  uint32_t u = __float_as_uint(f);
  uint32_t r = (u + 0x7FFFu + ((u >> 16) & 1u)) >> 16;
  return (ushort)r;
}

// ---------------------------------------------------------------------------
// KNN top-3, f64-exact selection. 8 threads per fine point, butterfly merge.
// 2048 blocks x 256 threads = 8 waves/SIMD (vs round-0's 1).
// ---------------------------------------------------------------------------
static __device__ __forceinline__ void ins3(double d, int i,
    double& b0, double& b1, double& b2, int& i0, int& i1, int& i2) {
  if (d < b2) {
    if (d < b1) {
      b2 = b1; i2 = i1;
      if (d < b0) { b1 = b0; i1 = i0; b0 = d; i0 = i; }
      else        { b1 = d;  i1 = i; }
    } else { b2 = d; i2 = i; }
  }
}

__global__ __launch_bounds__(256) void knn_kernel(
    const float* __restrict__ pos, const float* __restrict__ pos_skip,
    int4* __restrict__ idx_out, float4* __restrict__ w_out)
{
  __shared__ float pc[3072];
  const int b   = blockIdx.x >> 7;      // 128 blocks per batch
  const int blk = blockIdx.x & 127;     // 32 fine points per block
  for (int j = threadIdx.x; j < 3072; j += 256) pc[j] = pos[b * 3072 + j];
  __syncthreads();

  const int p   = threadIdx.x >> 3;     // point within block (0..31)
  const int sub = threadIdx.x & 7;      // candidate slice   (0..7)
  const int row = b * 4096 + blk * 32 + p;
  const double px = (double)pos_skip[(size_t)row * 3 + 0];
  const double py = (double)pos_skip[(size_t)row * 3 + 1];
  const double pz = (double)pos_skip[(size_t)row * 3 + 2];

  double b0 = 1e300, b1 = 1e300, b2 = 1e300;
  int i0 = 0, i1 = 0, i2 = 0;
  // thread `sub` scans candidates i = 8j+sub: disjoint cover of 0..1023,
  // consecutive lanes hit distinct LDS banks (stride 3 words).
#pragma unroll 4
  for (int j = 0; j < 128; ++j) {
    const int i = j * 8 + sub;
    double dx = (double)pc[i * 3 + 0] - px;
    double dy = (double)pc[i * 3 + 1] - py;
    double dz = (double)pc[i * 3 + 2] - pz;
    double d = dx * dx + dy * dy + dz * dz;
    ins3(d, i, b0, b1, b2, i0, i1, i2);
  }
  // butterfly merge across the 8 sub-lanes (disjoint candidate sets -> exact)
#pragma unroll
  for (int m = 1; m <= 4; m <<= 1) {
    double c0 = __shfl_xor(b0, m), c1 = __shfl_xor(b1, m), c2 = __shfl_xor(b2, m);
    int    j0 = __shfl_xor(i0, m), j1 = __shfl_xor(i1, m), j2 = __shfl_xor(i2, m);
    ins3(c0, j0, b0, b1, b2, i0, i1, i2);
    ins3(c1, j1, b0, b1, b2, i0, i1, i2);
    ins3(c2, j2, b0, b1, b2, i0, i1, i2);
  }
  if (sub == 0) {
    double w0 = 1.0 / (sqrt(b0) + 1e-8);
    double w1 = 1.0 / (sqrt(b1) + 1e-8);
    double w2 = 1.0 / (sqrt(b2) + 1e-8);
    double den = w0 + w1 + w2 + 1e-8;
    idx_out[row] = make_int4(i0, i1, i2, 0);
    w_out[row] = make_float4((float)(w0 / den), (float)(w1 / den), (float)(w2 / den), 0.f);
  }
}

// ---------------------------------------------------------------------------
// Fused: gather-interp (cols 0..511) + x_skip copy (cols 512..767) -> bf16.
// One row per 192-thread block; wave-aligned role split (waves 0-1 feat, 2 skip).
// ---------------------------------------------------------------------------
__global__ __launch_bounds__(192) void interp_gather_fused(
    const float* __restrict__ x, const float* __restrict__ xs,
    const int4* __restrict__ idx3, const float4* __restrict__ w3,
    ushort* __restrict__ hcat)
{
  const int row = blockIdx.x;
  const int tid = threadIdx.x;
  if (tid < 128) {
    const int b   = row >> 12;               // 4096 fine rows per batch
    const int4 id = idx3[row];
    const float4 w = w3[row];
    const float4* f0 = (const float4*)(x + (size_t)(b * 1024 + id.x) * 512);
    const float4* f1 = (const float4*)(x + (size_t)(b * 1024 + id.y) * 512);
    const float4* f2 = (const float4*)(x + (size_t)(b * 1024 + id.z) * 512);
    const float4 a = f0[tid], c1 = f1[tid], c2 = f2[tid];
    float4 v;
    v.x = w.x * a.x + w.y * c1.x + w.z * c2.x;
    v.y = w.x * a.y + w.y * c1.y + w.z * c2.y;
    v.z = w.x * a.z + w.y * c1.z + w.z * c2.z;
    v.w = w.x * a.w + w.y * c1.w + w.z * c2.w;
    ushort4 o;
    o.x = f2bf(v.x); o.y = f2bf(v.y); o.z = f2bf(v.z); o.w = f2bf(v.w);
    *(ushort4*)(hcat + (size_t)row * 768 + tid * 4) = o;
  } else {
    const int tc = tid - 128;                // 0..63, one float4 each
    const float4 v = *(const float4*)(xs + (size_t)row * 256 + tc * 4);
    ushort4 o;
    o.x = f2bf(v.x); o.y = f2bf(v.y); o.z = f2bf(v.z); o.w = f2bf(v.w);
    *(ushort4*)(hcat + (size_t)row * 768 + 512 + tc * 4) = o;
  }
}

// Both W1 [768x512] and W2 [512x512] f32 -> transposed bf16 in one launch.
__global__ __launch_bounds__(256) void convert_wt_both(
    const float* __restrict__ W1, const float* __restrict__ W2,
    ushort* __restrict__ W1t, ushort* __restrict__ W2t)
{
  const int id = blockIdx.x * 256 + threadIdx.x;
  if (id < 768 * 512) {
    const int n = id / 768, k = id - n * 768;      // W1t[n][k] = W1[k][n]
    W1t[id] = f2bf(W1[(size_t)k * 512 + n]);
  } else {
    const int id2 = id - 768 * 512;
    if (id2 < 512 * 512) {
      const int n = id2 >> 9, k = id2 & 511;       // W2t[n][k] = W2[k][n]
      W2t[id2] = f2bf(W2[(size_t)k * 512 + n]);
    }
  }
}

// ---------------------------------------------------------------------------
// bf16 MFMA GEMM: C = relu(A[M][K] * Bt[N][K]^T + bias), 128x128 tile, BK=64,
// 4 waves (2x2), 4x4 fragments of 16x16x32 per wave, global_load_lds width 16.
// ---------------------------------------------------------------------------
template<int K, bool OUT_BF16>
__global__ __launch_bounds__(256, 2) void gemm_bias_relu(
    const ushort* __restrict__ A, const ushort* __restrict__ Bt,
    const float* __restrict__ bias, void* __restrict__ Cout, int M, int N)
{
  constexpr int BM = 128, BN = 128, BK = 64;
  __shared__ ushort Asm[BM * BK];   // 16 KB, row-major [128][64]
  __shared__ ushort Bsm[BN * BK];   // 16 KB, row-major [128][64]
  const int tid  = threadIdx.x;
  const int lane = tid & 63;
  const int wave = tid >> 6;
  const int nbn  = N / BN;
  const int bm   = blockIdx.x / nbn;
  const int bn   = blockIdx.x - bm * nbn;
  const int row0 = bm * BM, col0 = bn * BN;
  const int wr = wave >> 1, wc = wave & 1;
  const int so = tid * 16;   // byte offset within a 4KB staging chunk

  f32x4 acc[4][4] = {};

  for (int kt = 0; kt < K / BK; ++kt) {
    __syncthreads();   // previous tile's reads complete before overwrite
    const int kbase = kt * BK;
#pragma unroll
    for (int i = 0; i < 4; ++i) {
      const int o  = i * 4096 + so;     // linear byte offset in 16KB tile
      const int r  = o >> 7;            // row (128B per row)
      const int cu = (o & 127) >> 1;    // ushort offset within row
      const ushort* ga = A + (size_t)(row0 + r) * K + kbase + cu;
      __builtin_amdgcn_global_load_lds(
          (const __attribute__((address_space(1))) void*)ga,
          (__attribute__((address_space(3))) void*)((char*)Asm + o), 16, 0, 0);
      const ushort* gb = Bt + (size_t)(col0 + r) * K + kbase + cu;
      __builtin_amdgcn_global_load_lds(
          (const __attribute__((address_space(1))) void*)gb,
          (__attribute__((address_space(3))) void*)((char*)Bsm + o), 16, 0, 0);
    }
    __syncthreads();   // compiler emits vmcnt(0) drain before barrier

#pragma unroll
    for (int kk = 0; kk < 2; ++kk) {
      short8 af[4], bfr[4];
#pragma unroll
      for (int mi = 0; mi < 4; ++mi)
        af[mi] = *(const short8*)&Asm[(wr * 64 + mi * 16 + (lane & 15)) * BK + kk * 32 + (lane >> 4) * 8];
#pragma unroll
      for (int ni = 0; ni < 4; ++ni)
        bfr[ni] = *(const short8*)&Bsm[(wc * 64 + ni * 16 + (lane & 15)) * BK + kk * 32 + (lane >> 4) * 8];
#pragma unroll
      for (int mi = 0; mi < 4; ++mi)
#pragma unroll
        for (int ni = 0; ni < 4; ++ni)
          acc[mi][ni] = __builtin_amdgcn_mfma_f32_16x16x32_bf16(af[mi], bfr[ni], acc[mi][ni], 0, 0, 0);
    }
  }

  // epilogue: bias + relu; C/D layout: col = lane&15, row = (lane>>4)*4 + reg
  const int lc = lane & 15, lr = lane >> 4;
#pragma unroll
  for (int mi = 0; mi < 4; ++mi) {
#pragma unroll
    for (int ni = 0; ni < 4; ++ni) {
      const int col = col0 + wc * 64 + ni * 16 + lc;
      const float bv = bias[col];
      const int rbase = row0 + wr * 64 + mi * 16 + lr * 4;
#pragma unroll
      for (int r = 0; r < 4; ++r) {
        float v = acc[mi][ni][r] + bv;
        v = v > 0.f ? v : 0.f;
        if (OUT_BF16) ((ushort*)Cout)[(size_t)(rbase + r) * N + col] = f2bf(v);
        else          ((float*)Cout)[(size_t)(rbase + r) * N + col] = v;
      }
    }
  }
}

// ---------------------------------------------------------------------------
extern "C" void kernel_launch(void* const* d_in, const int* in_sizes, int n_in,
                              void* d_out, int out_size, void* d_ws, size_t ws_size,
                              hipStream_t stream) {
  const float* x        = (const float*)d_in[0];   // [16384, 512]
  const float* pos      = (const float*)d_in[1];   // [16384, 3]
  const float* x_skip   = (const float*)d_in[3];   // [65536, 256]
  const float* pos_skip = (const float*)d_in[4];   // [65536, 3]
  const float* W1       = (const float*)d_in[6];   // [768, 512]
  const float* b1       = (const float*)d_in[7];   // [512]
  const float* W2       = (const float*)d_in[8];   // [512, 512]
  const float* b2       = (const float*)d_in[9];   // [512]

  // d_out (134.2 MB f32) doubles as scratch for hcat bf16 (100.7 MB):
  // fully consumed by GEMM1 before GEMM2 overwrites d_out with the output.
  ushort* hcat = (ushort*)d_out;                       // [65536][768] bf16

  char* ws = (char*)d_ws;
  ushort* h2   = (ushort*)ws;                          // [65536][512] bf16, 67108864 B
  ushort* W1t  = (ushort*)(ws + 67108864);             // [512][768]  bf16, 786432 B
  ushort* W2t  = (ushort*)(ws + 67895296);             // [512][512]  bf16, 524288 B
  int4*   idx3 = (int4*)  (ws + 68419584);             // [65536] int4, 1 MB
  float4* w3   = (float4*)(ws + 69468160);             // [65536] float4, 1 MB

  knn_kernel<<<2048, 256, 0, stream>>>(pos, pos_skip, idx3, w3);
  convert_wt_both<<<(768 * 512 + 512 * 512 + 255) / 256, 256, 0, stream>>>(W1, W2, W1t, W2t);
  interp_gather_fused<<<65536, 192, 0, stream>>>(x, x_skip, idx3, w3, hcat);

  // GEMM1: [65536x768] x [768x512] -> h2 bf16 (ws)
  gemm_bias_relu<768, true><<<2048, 256, 0, stream>>>(hcat, W1t, b1, (void*)h2, 65536, 512);
  // GEMM2: [65536x512] x [512x512] -> d_out f32
  gemm_bias_relu<512, false><<<2048, 256, 0, stream>>>(h2, W2t, b2, d_out, 65536, 512);
}

// Round 3
// 266.731 us; speedup vs baseline: 1.9361x; 1.9361x over previous
//
#include <hip/hip_runtime.h>
#include <stdint.h>

typedef __attribute__((ext_vector_type(8))) short short8;
typedef __attribute__((ext_vector_type(4))) float f32x4;

static __device__ __forceinline__ ushort f2bf(float f) {
  uint32_t u = __float_as_uint(f);
  uint32_t r = (u + 0x7FFFu + ((u >> 16) & 1u)) >> 16;
  return (ushort)r;
}

// ---------------------------------------------------------------------------
// KNN top-3, f64-exact selection, BRANCHLESS insert (select network).
// 4 threads per fine point (split candidate scan), butterfly merge via shfl.
// 1024 blocks x 256 threads = 4 waves/SIMD.
// ---------------------------------------------------------------------------
static __device__ __forceinline__ void ins3b(double d, int i,
    double& b0, double& b1, double& b2, int& i0, int& i1, int& i2) {
  // maintained sorted b0<=b1<=b2; pure ternaries -> v_cndmask, no branches
  const bool c0 = d < b0, c1 = d < b1, c2 = d < b2;
  const double nb0 = c0 ? d : b0;
  const int    ni0 = c0 ? i : i0;
  const double nb1 = c0 ? b0 : (c1 ? d : b1);
  const int    ni1 = c0 ? i0 : (c1 ? i : i1);
  const double nb2 = c1 ? b1 : (c2 ? d : b2);
  const int    ni2 = c1 ? i1 : (c2 ? i : i2);
  b0 = nb0; b1 = nb1; b2 = nb2; i0 = ni0; i1 = ni1; i2 = ni2;
}

__global__ __launch_bounds__(256) void knn_kernel(
    const float* __restrict__ pos, const float* __restrict__ pos_skip,
    int4* __restrict__ idx_out, float4* __restrict__ w_out)
{
  __shared__ float pc[3072];
  const int b   = blockIdx.x >> 6;      // 64 blocks per batch
  const int blk = blockIdx.x & 63;      // 64 fine points per block
  for (int j = threadIdx.x; j < 3072; j += 256) pc[j] = pos[b * 3072 + j];
  __syncthreads();

  const int p   = threadIdx.x >> 2;     // point within block (0..63)
  const int sub = threadIdx.x & 3;      // candidate slice   (0..3)
  const int row = b * 4096 + blk * 64 + p;
  const double px = (double)pos_skip[(size_t)row * 3 + 0];
  const double py = (double)pos_skip[(size_t)row * 3 + 1];
  const double pz = (double)pos_skip[(size_t)row * 3 + 2];

  double b0 = 1e300, b1 = 1e300, b2 = 1e300;
  int i0 = 0, i1 = 0, i2 = 0;
  // thread `sub` scans candidates i = 4j+sub: disjoint cover of 0..1023.
#pragma unroll 4
  for (int j = 0; j < 256; ++j) {
    const int i = j * 4 + sub;
    const double dx = (double)pc[i * 3 + 0] - px;
    const double dy = (double)pc[i * 3 + 1] - py;
    const double dz = (double)pc[i * 3 + 2] - pz;
    const double d = dx * dx + dy * dy + dz * dz;
    ins3b(d, i, b0, b1, b2, i0, i1, i2);
  }
  // butterfly merge across the 4 sub-lanes (disjoint candidate sets -> exact)
#pragma unroll
  for (int m = 1; m <= 2; m <<= 1) {
    const double c0 = __shfl_xor(b0, m), c1 = __shfl_xor(b1, m), c2 = __shfl_xor(b2, m);
    const int    j0 = __shfl_xor(i0, m), j1 = __shfl_xor(i1, m), j2 = __shfl_xor(i2, m);
    ins3b(c0, j0, b0, b1, b2, i0, i1, i2);
    ins3b(c1, j1, b0, b1, b2, i0, i1, i2);
    ins3b(c2, j2, b0, b1, b2, i0, i1, i2);
  }
  if (sub == 0) {
    const double w0 = 1.0 / (sqrt(b0) + 1e-8);
    const double w1 = 1.0 / (sqrt(b1) + 1e-8);
    const double w2 = 1.0 / (sqrt(b2) + 1e-8);
    const double den = w0 + w1 + w2 + 1e-8;
    idx_out[row] = make_int4(i0, i1, i2, 0);
    w_out[row] = make_float4((float)(w0 / den), (float)(w1 / den), (float)(w2 / den), 0.f);
  }
}

// ---------------------------------------------------------------------------
// Fused: gather-interp (cols 0..511) + x_skip copy (cols 512..767) -> bf16.
// One row per 192-thread block; wave-aligned role split (waves 0-1 feat, 2 skip).
// ---------------------------------------------------------------------------
__global__ __launch_bounds__(192) void interp_gather_fused(
    const float* __restrict__ x, const float* __restrict__ xs,
    const int4* __restrict__ idx3, const float4* __restrict__ w3,
    ushort* __restrict__ hcat)
{
  const int row = blockIdx.x;
  const int tid = threadIdx.x;
  if (tid < 128) {
    const int b   = row >> 12;               // 4096 fine rows per batch
    const int4 id = idx3[row];
    const float4 w = w3[row];
    const float4* f0 = (const float4*)(x + (size_t)(b * 1024 + id.x) * 512);
    const float4* f1 = (const float4*)(x + (size_t)(b * 1024 + id.y) * 512);
    const float4* f2 = (const float4*)(x + (size_t)(b * 1024 + id.z) * 512);
    const float4 a = f0[tid], c1 = f1[tid], c2 = f2[tid];
    float4 v;
    v.x = w.x * a.x + w.y * c1.x + w.z * c2.x;
    v.y = w.x * a.y + w.y * c1.y + w.z * c2.y;
    v.z = w.x * a.z + w.y * c1.z + w.z * c2.z;
    v.w = w.x * a.w + w.y * c1.w + w.z * c2.w;
    ushort4 o;
    o.x = f2bf(v.x); o.y = f2bf(v.y); o.z = f2bf(v.z); o.w = f2bf(v.w);
    *(ushort4*)(hcat + (size_t)row * 768 + tid * 4) = o;
  } else {
    const int tc = tid - 128;                // 0..63, one float4 each
    const float4 v = *(const float4*)(xs + (size_t)row * 256 + tc * 4);
    ushort4 o;
    o.x = f2bf(v.x); o.y = f2bf(v.y); o.z = f2bf(v.z); o.w = f2bf(v.w);
    *(ushort4*)(hcat + (size_t)row * 768 + 512 + tc * 4) = o;
  }
}

// Both W1 [768x512] and W2 [512x512] f32 -> transposed bf16 in one launch.
__global__ __launch_bounds__(256) void convert_wt_both(
    const float* __restrict__ W1, const float* __restrict__ W2,
    ushort* __restrict__ W1t, ushort* __restrict__ W2t)
{
  const int id = blockIdx.x * 256 + threadIdx.x;
  if (id < 768 * 512) {
    const int n = id / 768, k = id - n * 768;      // W1t[n][k] = W1[k][n]
    W1t[id] = f2bf(W1[(size_t)k * 512 + n]);
  } else {
    const int id2 = id - 768 * 512;
    if (id2 < 512 * 512) {
      const int n = id2 >> 9, k = id2 & 511;       // W2t[n][k] = W2[k][n]
      W2t[id2] = f2bf(W2[(size_t)k * 512 + n]);
    }
  }
}

// ---------------------------------------------------------------------------
// bf16 MFMA GEMM: C = relu(A[M][K] * Bt[N][K]^T + bias), 128x128 tile, BK=64,
// 4 waves (2x2), 4x4 fragments of 16x16x32 per wave, global_load_lds width 16.
// ---------------------------------------------------------------------------
template<int K, bool OUT_BF16>
__global__ __launch_bounds__(256, 2) void gemm_bias_relu(
    const ushort* __restrict__ A, const ushort* __restrict__ Bt,
    const float* __restrict__ bias, void* __restrict__ Cout, int M, int N)
{
  constexpr int BM = 128, BN = 128, BK = 64;
  __shared__ ushort Asm[BM * BK];   // 16 KB, row-major [128][64]
  __shared__ ushort Bsm[BN * BK];   // 16 KB, row-major [128][64]
  const int tid  = threadIdx.x;
  const int lane = tid & 63;
  const int wave = tid >> 6;
  const int nbn  = N / BN;
  const int bm   = blockIdx.x / nbn;
  const int bn   = blockIdx.x - bm * nbn;
  const int row0 = bm * BM, col0 = bn * BN;
  const int wr = wave >> 1, wc = wave & 1;
  const int so = tid * 16;   // byte offset within a 4KB staging chunk

  f32x4 acc[4][4] = {};

  for (int kt = 0; kt < K / BK; ++kt) {
    __syncthreads();   // previous tile's reads complete before overwrite
    const int kbase = kt * BK;
#pragma unroll
    for (int i = 0; i < 4; ++i) {
      const int o  = i * 4096 + so;     // linear byte offset in 16KB tile
      const int r  = o >> 7;            // row (128B per row)
      const int cu = (o & 127) >> 1;    // ushort offset within row
      const ushort* ga = A + (size_t)(row0 + r) * K + kbase + cu;
      __builtin_amdgcn_global_load_lds(
          (const __attribute__((address_space(1))) void*)ga,
          (__attribute__((address_space(3))) void*)((char*)Asm + o), 16, 0, 0);
      const ushort* gb = Bt + (size_t)(col0 + r) * K + kbase + cu;
      __builtin_amdgcn_global_load_lds(
          (const __attribute__((address_space(1))) void*)gb,
          (__attribute__((address_space(3))) void*)((char*)Bsm + o), 16, 0, 0);
    }
    __syncthreads();   // compiler emits vmcnt(0) drain before barrier

#pragma unroll
    for (int kk = 0; kk < 2; ++kk) {
      short8 af[4], bfr[4];
#pragma unroll
      for (int mi = 0; mi < 4; ++mi)
        af[mi] = *(const short8*)&Asm[(wr * 64 + mi * 16 + (lane & 15)) * BK + kk * 32 + (lane >> 4) * 8];
#pragma unroll
      for (int ni = 0; ni < 4; ++ni)
        bfr[ni] = *(const short8*)&Bsm[(wc * 64 + ni * 16 + (lane & 15)) * BK + kk * 32 + (lane >> 4) * 8];
#pragma unroll
      for (int mi = 0; mi < 4; ++mi)
#pragma unroll
        for (int ni = 0; ni < 4; ++ni)
          acc[mi][ni] = __builtin_amdgcn_mfma_f32_16x16x32_bf16(af[mi], bfr[ni], acc[mi][ni], 0, 0, 0);
    }
  }

  // epilogue: bias + relu; C/D layout: col = lane&15, row = (lane>>4)*4 + reg
  const int lc = lane & 15, lr = lane >> 4;
#pragma unroll
  for (int mi = 0; mi < 4; ++mi) {
#pragma unroll
    for (int ni = 0; ni < 4; ++ni) {
      const int col = col0 + wc * 64 + ni * 16 + lc;
      const float bv = bias[col];
      const int rbase = row0 + wr * 64 + mi * 16 + lr * 4;
#pragma unroll
      for (int r = 0; r < 4; ++r) {
        float v = acc[mi][ni][r] + bv;
        v = v > 0.f ? v : 0.f;
        if (OUT_BF16) ((ushort*)Cout)[(size_t)(rbase + r) * N + col] = f2bf(v);
        else          ((float*)Cout)[(size_t)(rbase + r) * N + col] = v;
      }
    }
  }
}

// ---------------------------------------------------------------------------
extern "C" void kernel_launch(void* const* d_in, const int* in_sizes, int n_in,
                              void* d_out, int out_size, void* d_ws, size_t ws_size,
                              hipStream_t stream) {
  const float* x        = (const float*)d_in[0];   // [16384, 512]
  const float* pos      = (const float*)d_in[1];   // [16384, 3]
  const float* x_skip   = (const float*)d_in[3];   // [65536, 256]
  const float* pos_skip = (const float*)d_in[4];   // [65536, 3]
  const float* W1       = (const float*)d_in[6];   // [768, 512]
  const float* b1       = (const float*)d_in[7];   // [512]
  const float* W2       = (const float*)d_in[8];   // [512, 512]
  const float* b2       = (const float*)d_in[9];   // [512]

  // d_out (134.2 MB f32) doubles as scratch for hcat bf16 (100.7 MB):
  // fully consumed by GEMM1 before GEMM2 overwrites d_out with the output.
  ushort* hcat = (ushort*)d_out;                       // [65536][768] bf16

  char* ws = (char*)d_ws;
  ushort* h2   = (ushort*)ws;                          // [65536][512] bf16, 67108864 B
  ushort* W1t  = (ushort*)(ws + 67108864);             // [512][768]  bf16, 786432 B
  ushort* W2t  = (ushort*)(ws + 67895296);             // [512][512]  bf16, 524288 B
  int4*   idx3 = (int4*)  (ws + 68419584);             // [65536] int4, 1 MB
  float4* w3   = (float4*)(ws + 69468160);             // [65536] float4, 1 MB

  knn_kernel<<<1024, 256, 0, stream>>>(pos, pos_skip, idx3, w3);
  convert_wt_both<<<(768 * 512 + 512 * 512 + 255) / 256, 256, 0, stream>>>(W1, W2, W1t, W2t);
  interp_gather_fused<<<65536, 192, 0, stream>>>(x, x_skip, idx3, w3, hcat);

  // GEMM1: [65536x768] x [768x512] -> h2 bf16 (ws)
  gemm_bias_relu<768, true><<<2048, 256, 0, stream>>>(hcat, W1t, b1, (void*)h2, 65536, 512);
  // GEMM2: [65536x512] x [512x512] -> d_out f32
  gemm_bias_relu<512, false><<<2048, 256, 0, stream>>>(h2, W2t, b2, d_out, 65536, 512);
}

// Round 4
// 246.559 us; speedup vs baseline: 2.0945x; 1.0818x over previous
//
#include <hip/hip_runtime.h>
#include <stdint.h>

typedef __attribute__((ext_vector_type(8))) short short8;
typedef __attribute__((ext_vector_type(4))) float f32x4;

static __device__ __forceinline__ ushort f2bf(float f) {
  uint32_t u = __float_as_uint(f);
  uint32_t r = (u + 0x7FFFu + ((u >> 16) & 1u)) >> 16;
  return (ushort)r;
}

// ---------------------------------------------------------------------------
// KNN top-3, f64-exact selection, branchless insert. 4 threads/point.
// ---------------------------------------------------------------------------
static __device__ __forceinline__ void ins3b(double d, int i,
    double& b0, double& b1, double& b2, int& i0, int& i1, int& i2) {
  const bool c0 = d < b0, c1 = d < b1, c2 = d < b2;
  const double nb0 = c0 ? d : b0;
  const int    ni0 = c0 ? i : i0;
  const double nb1 = c0 ? b0 : (c1 ? d : b1);
  const int    ni1 = c0 ? i0 : (c1 ? i : i1);
  const double nb2 = c1 ? b1 : (c2 ? d : b2);
  const int    ni2 = c1 ? i1 : (c2 ? i : i2);
  b0 = nb0; b1 = nb1; b2 = nb2; i0 = ni0; i1 = ni1; i2 = ni2;
}

__global__ __launch_bounds__(256) void knn_kernel(
    const float* __restrict__ pos, const float* __restrict__ pos_skip,
    int4* __restrict__ idx_out, float4* __restrict__ w_out)
{
  __shared__ float pc[3072];
  const int b   = blockIdx.x >> 6;      // 64 blocks per batch
  const int blk = blockIdx.x & 63;      // 64 fine points per block
  for (int j = threadIdx.x; j < 3072; j += 256) pc[j] = pos[b * 3072 + j];
  __syncthreads();

  const int p   = threadIdx.x >> 2;     // point within block (0..63)
  const int sub = threadIdx.x & 3;      // candidate slice   (0..3)
  const int row = b * 4096 + blk * 64 + p;
  const double px = (double)pos_skip[(size_t)row * 3 + 0];
  const double py = (double)pos_skip[(size_t)row * 3 + 1];
  const double pz = (double)pos_skip[(size_t)row * 3 + 2];

  double b0 = 1e300, b1 = 1e300, b2 = 1e300;
  int i0 = 0, i1 = 0, i2 = 0;
#pragma unroll 4
  for (int j = 0; j < 256; ++j) {
    const int i = j * 4 + sub;
    const double dx = (double)pc[i * 3 + 0] - px;
    const double dy = (double)pc[i * 3 + 1] - py;
    const double dz = (double)pc[i * 3 + 2] - pz;
    const double d = dx * dx + dy * dy + dz * dz;
    ins3b(d, i, b0, b1, b2, i0, i1, i2);
  }
#pragma unroll
  for (int m = 1; m <= 2; m <<= 1) {
    const double c0 = __shfl_xor(b0, m), c1 = __shfl_xor(b1, m), c2 = __shfl_xor(b2, m);
    const int    j0 = __shfl_xor(i0, m), j1 = __shfl_xor(i1, m), j2 = __shfl_xor(i2, m);
    ins3b(c0, j0, b0, b1, b2, i0, i1, i2);
    ins3b(c1, j1, b0, b1, b2, i0, i1, i2);
    ins3b(c2, j2, b0, b1, b2, i0, i1, i2);
  }
  if (sub == 0) {
    const double w0 = 1.0 / (sqrt(b0) + 1e-8);
    const double w1 = 1.0 / (sqrt(b1) + 1e-8);
    const double w2 = 1.0 / (sqrt(b2) + 1e-8);
    const double den = w0 + w1 + w2 + 1e-8;
    idx_out[row] = make_int4(i0, i1, i2, 0);
    w_out[row] = make_float4((float)(w0 / den), (float)(w1 / den), (float)(w2 / den), 0.f);
  }
}

// ---------------------------------------------------------------------------
// Fused gather-interp + skip-copy, wave-per-row grid-stride.
// 2048 blocks x 256 threads = 8192 waves; 8 rows/wave; no barriers.
// ---------------------------------------------------------------------------
__global__ __launch_bounds__(256) void interp_gather_fused(
    const float* __restrict__ x, const float* __restrict__ xs,
    const int4* __restrict__ idx3, const float4* __restrict__ w3,
    ushort* __restrict__ hcat)
{
  const int wid  = (blockIdx.x * 256 + threadIdx.x) >> 6;  // 0..8191
  const int lane = threadIdx.x & 63;
  for (int row = wid; row < 65536; row += 8192) {
    const int b = row >> 12;                   // 4096 fine rows per batch
    const int4 id = idx3[row];
    const float4 w = w3[row];
    const float* base = x + (size_t)b * 1024 * 512;
    const float4* f0 = (const float4*)(base + (size_t)id.x * 512);
    const float4* f1 = (const float4*)(base + (size_t)id.y * 512);
    const float4* f2 = (const float4*)(base + (size_t)id.z * 512);
    ushort* orow = hcat + (size_t)row * 768;
#pragma unroll
    for (int it = 0; it < 2; ++it) {
      const int tc = it * 64 + lane;           // float4 slot 0..127
      const float4 a = f0[tc], c1 = f1[tc], c2 = f2[tc];
      float4 v;
      v.x = w.x * a.x + w.y * c1.x + w.z * c2.x;
      v.y = w.x * a.y + w.y * c1.y + w.z * c2.y;
      v.z = w.x * a.z + w.y * c1.z + w.z * c2.z;
      v.w = w.x * a.w + w.y * c1.w + w.z * c2.w;
      ushort4 o;
      o.x = f2bf(v.x); o.y = f2bf(v.y); o.z = f2bf(v.z); o.w = f2bf(v.w);
      *(ushort4*)(orow + tc * 4) = o;
    }
    const float4 v = *(const float4*)(xs + (size_t)row * 256 + lane * 4);
    ushort4 o;
    o.x = f2bf(v.x); o.y = f2bf(v.y); o.z = f2bf(v.z); o.w = f2bf(v.w);
    *(ushort4*)(orow + 512 + lane * 4) = o;
  }
}

// Both W1 [768x512] and W2 [512x512] f32 -> transposed bf16 in one launch.
__global__ __launch_bounds__(256) void convert_wt_both(
    const float* __restrict__ W1, const float* __restrict__ W2,
    ushort* __restrict__ W1t, ushort* __restrict__ W2t)
{
  const int id = blockIdx.x * 256 + threadIdx.x;
  if (id < 768 * 512) {
    const int n = id / 768, k = id - n * 768;      // W1t[n][k] = W1[k][n]
    W1t[id] = f2bf(W1[(size_t)k * 512 + n]);
  } else {
    const int id2 = id - 768 * 512;
    if (id2 < 512 * 512) {
      const int n = id2 >> 9, k = id2 & 511;       // W2t[n][k] = W2[k][n]
      W2t[id2] = f2bf(W2[(size_t)k * 512 + n]);
    }
  }
}

// ---------------------------------------------------------------------------
// bf16 MFMA GEMM: C = relu(A[M][K] * Bt[N][K]^T + bias). 128x128 tile, BK=64.
// Min-2-phase double-buffered LDS (T3 recipe), T2 both-sides XOR swizzle
// (linear LDS dest for global_load_lds + pre-swizzled SOURCE + swizzled read),
// T1 XCD-aware blockIdx swizzle (grid % 8 == 0).
// ---------------------------------------------------------------------------
template<int K, bool OUT_BF16>
__global__ __launch_bounds__(256, 2) void gemm_bias_relu(
    const ushort* __restrict__ A, const ushort* __restrict__ Bt,
    const float* __restrict__ bias, void* __restrict__ Cout, int M, int N)
{
  constexpr int BM = 128, BN = 128, BK = 64, NT = K / BK;
  __shared__ ushort Asm[2][BM * BK];   // 2 x 16 KB
  __shared__ ushort Bsm[2][BN * BK];   // 2 x 16 KB
  const int tid  = threadIdx.x;
  const int lane = tid & 63;
  const int wave = tid >> 6;

  // T1: bijective XCD swizzle (gridDim.x % 8 == 0)
  const int cpx = gridDim.x >> 3;
  const int wgid = (blockIdx.x & 7) * cpx + (blockIdx.x >> 3);
  const int nbn  = N / BN;
  const int bm   = wgid / nbn;
  const int bn   = wgid - bm * nbn;
  const int row0 = bm * BM, col0 = bn * BN;
  const int wr = wave >> 1, wc = wave & 1;
  const int so = tid * 16;   // byte offset within a 4KB staging chunk

  f32x4 acc[4][4] = {};

  // T2 swizzle: LDS slot (r, s) holds global 16B-column (s ^ (r&7)).
  auto stage = [&](int buf, int kt) {
    const int kbase = kt * BK;
#pragma unroll
    for (int i = 0; i < 4; ++i) {
      const int o  = i * 4096 + so;          // linear byte offset in 16KB tile
      const int r  = o >> 7;                 // row (128 B per row)
      const int s  = (o & 127) >> 4;         // 16B slot 0..7
      const int cu = ((s ^ (r & 7)) << 3);   // pre-swizzled source column
      __builtin_amdgcn_global_load_lds(
          (const __attribute__((address_space(1))) void*)(A + (size_t)(row0 + r) * K + kbase + cu),
          (__attribute__((address_space(3))) void*)((char*)&Asm[buf][0] + o), 16, 0, 0);
      __builtin_amdgcn_global_load_lds(
          (const __attribute__((address_space(1))) void*)(Bt + (size_t)(col0 + r) * K + kbase + cu),
          (__attribute__((address_space(3))) void*)((char*)&Bsm[buf][0] + o), 16, 0, 0);
    }
  };

  auto compute = [&](int buf) {
#pragma unroll
    for (int kk = 0; kk < 2; ++kk) {
      short8 af[4], bfr[4];
#pragma unroll
      for (int mi = 0; mi < 4; ++mi) {
        const int ra = wr * 64 + mi * 16 + (lane & 15);
        const int s  = kk * 4 + (lane >> 4);
        af[mi] = *(const short8*)&Asm[buf][ra * BK + ((s ^ (ra & 7)) << 3)];
      }
#pragma unroll
      for (int ni = 0; ni < 4; ++ni) {
        const int rb = wc * 64 + ni * 16 + (lane & 15);
        const int s  = kk * 4 + (lane >> 4);
        bfr[ni] = *(const short8*)&Bsm[buf][rb * BK + ((s ^ (rb & 7)) << 3)];
      }
#pragma unroll
      for (int mi = 0; mi < 4; ++mi)
#pragma unroll
        for (int ni = 0; ni < 4; ++ni)
          acc[mi][ni] = __builtin_amdgcn_mfma_f32_16x16x32_bf16(af[mi], bfr[ni], acc[mi][ni], 0, 0, 0);
    }
  };

  stage(0, 0);
  __syncthreads();
  int cur = 0;
#pragma unroll 1
  for (int kt = 0; kt < NT - 1; ++kt) {
    stage(cur ^ 1, kt + 1);   // next tile's loads fly during compute
    compute(cur);
    __syncthreads();          // drains vmcnt (stage done) + all reads of cur
    cur ^= 1;
  }
  compute(cur);

  // epilogue: bias + relu; C/D layout: col = lane&15, row = (lane>>4)*4 + reg
  const int lc = lane & 15, lr = lane >> 4;
#pragma unroll
  for (int mi = 0; mi < 4; ++mi) {
#pragma unroll
    for (int ni = 0; ni < 4; ++ni) {
      const int col = col0 + wc * 64 + ni * 16 + lc;
      const float bv = bias[col];
      const int rbase = row0 + wr * 64 + mi * 16 + lr * 4;
#pragma unroll
      for (int r = 0; r < 4; ++r) {
        float v = acc[mi][ni][r] + bv;
        v = v > 0.f ? v : 0.f;
        if (OUT_BF16) ((ushort*)Cout)[(size_t)(rbase + r) * N + col] = f2bf(v);
        else          ((float*)Cout)[(size_t)(rbase + r) * N + col] = v;
      }
    }
  }
}

// ---------------------------------------------------------------------------
extern "C" void kernel_launch(void* const* d_in, const int* in_sizes, int n_in,
                              void* d_out, int out_size, void* d_ws, size_t ws_size,
                              hipStream_t stream) {
  const float* x        = (const float*)d_in[0];   // [16384, 512]
  const float* pos      = (const float*)d_in[1];   // [16384, 3]
  const float* x_skip   = (const float*)d_in[3];   // [65536, 256]
  const float* pos_skip = (const float*)d_in[4];   // [65536, 3]
  const float* W1       = (const float*)d_in[6];   // [768, 512]
  const float* b1       = (const float*)d_in[7];   // [512]
  const float* W2       = (const float*)d_in[8];   // [512, 512]
  const float* b2       = (const float*)d_in[9];   // [512]

  // d_out (134.2 MB f32) doubles as scratch for hcat bf16 (100.7 MB):
  // fully consumed by GEMM1 before GEMM2 overwrites d_out with the output.
  ushort* hcat = (ushort*)d_out;                       // [65536][768] bf16

  char* ws = (char*)d_ws;
  ushort* h2   = (ushort*)ws;                          // [65536][512] bf16, 67108864 B
  ushort* W1t  = (ushort*)(ws + 67108864);             // [512][768]  bf16, 786432 B
  ushort* W2t  = (ushort*)(ws + 67895296);             // [512][512]  bf16, 524288 B
  int4*   idx3 = (int4*)  (ws + 68419584);             // [65536] int4, 1 MB
  float4* w3   = (float4*)(ws + 69468160);             // [65536] float4, 1 MB

  knn_kernel<<<1024, 256, 0, stream>>>(pos, pos_skip, idx3, w3);
  convert_wt_both<<<(768 * 512 + 512 * 512 + 255) / 256, 256, 0, stream>>>(W1, W2, W1t, W2t);
  interp_gather_fused<<<2048, 256, 0, stream>>>(x, x_skip, idx3, w3, hcat);

  // GEMM1: [65536x768] x [768x512] -> h2 bf16 (ws)
  gemm_bias_relu<768, true><<<2048, 256, 0, stream>>>(hcat, W1t, b1, (void*)h2, 65536, 512);
  // GEMM2: [65536x512] x [512x512] -> d_out f32
  gemm_bias_relu<512, false><<<2048, 256, 0, stream>>>(h2, W2t, b2, d_out, 65536, 512);
}